// Round 6
// baseline (8367.523 us; speedup 1.0000x reference)
//
#include <hip/hip_runtime.h>
#include <math.h>

// Problem constants
#define BB 16      // batch
#define TT 16      // time (input)
#define EE 128     // embed
#define KS 15      // kernel
#define MM 41      // map size
#define OO 4       // orientations
#define VR 7       // view range
#define SS 27      // localize output spatial (41 - 2*7)
#define NSTEP 15
#define PP (MM*MM)          // 1681
#define NROWS (BB*PP)       // 26896

#define RAWS_OFF 0
#define SPS_OFF  1613760            // 16*15*4*1681
#define MAPS_OFF 3227520            // 2*SPS

#define PM 55               // padded map (41 + 2*7)
#define PMSZ (PM*PM)        // 3025

#define NEQ 32              // localize e-chunks (4 e each)

__device__ __forceinline__ float sigf(float x) { return 1.f / (1.f + expf(-x)); }

// rotate kernel coords (r,c) by o*90deg CCW -> source (ir,ic) in 15x15 image
__device__ __forceinline__ int rotoff(int o, int r, int c) {
    int ir, ic;
    if (o == 0)      { ir = r;      ic = c;      }
    else if (o == 1) { ir = c;      ic = 14 - r; }
    else if (o == 2) { ir = 14 - r; ic = 14 - c; }
    else             { ir = 14 - c; ic = r;      }
    return ir * 15 + ic;
}

// ---------------- pose init: zeros + one-hot at (o=0, 20,20) ----------------
__global__ void k_init(float* __restrict__ pose) {
    int idx = blockIdx.x * 256 + threadIdx.x;
    if (idx < BB * OO * MM * MM) {
        int r = idx % (OO * MM * MM);
        pose[idx] = (r == (20 * MM + 20)) ? 1.f : 0.f;
    }
}

// ---------------- weight prep: Wc[k][jp], jp = jj*4+g, j = g*128+jj ----------
__global__ void k_prep(const float* __restrict__ wih, const float* __restrict__ whh,
                       const float* __restrict__ bih, const float* __restrict__ bhh,
                       float* __restrict__ Wc, float* __restrict__ bc) {
    int idx = blockIdx.x * 256 + threadIdx.x;   // [0, 256*512)
    int k = idx >> 9, jp = idx & 511;
    int jj = jp >> 2, g = jp & 3, j = g * 128 + jj;
    Wc[idx] = (k < 128) ? wih[j * 128 + k] : whh[j * 128 + (k - 128)];
    if (idx < 512) {
        int jj2 = idx >> 2, g2 = idx & 3, j2 = g2 * 128 + jj2;
        bc[idx] = bih[j2] + bhh[j2];
    }
}

// ---------------- register: conv-transpose of pose with rotated images -------
// reg[b, p=(y,x), e] = sum_{o,dy,dx} pose[b,o,y+7-dy,x+7-dx] * rot_o(img[b,t])[e,dy,dx]
// Reformulated over IMG taps (R,C): weight read once, 4 inverse-rotated pose taps.
// Padded pose ps[r][c] = pose[r-7][c-7]; pbase = (y+14)*PM + (x+14).
__global__ __launch_bounds__(256) void k_register(const float* __restrict__ images,
                                                  const float* __restrict__ pose,
                                                  float* __restrict__ reg, int t) {
    __shared__ float ps[OO * PMSZ];      // 48.4 KB padded pose
    __shared__ float wsm[225][36];       // 32.4 KB img quarter, transposed (+pad)
    const int p0 = blockIdx.x * 256;
    const int eq = blockIdx.y;           // e quarter: 32 e
    const int b  = blockIdx.z;
    const int tid = threadIdx.x;

    // stage padded pose (zeros in halo)
    for (int i = tid; i < OO * PMSZ; i += 256) {
        int o = i / PMSZ, rem = i % PMSZ, r = rem / PM, c = rem % PM;
        float v = 0.f;
        if (r >= VR && r < VR + MM && c >= VR && c < VR + MM)
            v = pose[(((size_t)b * OO + o) * MM + (r - VR)) * MM + (c - VR)];
        ps[i] = v;
    }
    // stage img quarter transposed: wsm[k][e] = img[e][k]
    const float* img = images + ((size_t)(b * TT + t) * EE + eq * 32) * 225;
    for (int i = tid; i < 32 * 225; i += 256) {
        int e = i / 225, k = i - e * 225;
        wsm[k][e] = img[e * 225 + k];
    }
    __syncthreads();

    const int px = tid & 63;
    const int ec = tid >> 6;             // 0..3, uniform per wave -> wsm broadcast
    int pbase[4];
    #pragma unroll
    for (int i = 0; i < 4; ++i) {
        int p = p0 + px + 64 * i;
        int pc = (p < PP) ? p : 0;
        int y = pc / MM, x = pc - y * MM;
        pbase[i] = (y + 2 * VR) * PM + (x + 2 * VR);
    }

    float acc[4][8];
    #pragma unroll
    for (int i = 0; i < 4; ++i)
        #pragma unroll
        for (int j = 0; j < 8; ++j) acc[i][j] = 0.f;

    for (int R = 0; R < 15; ++R) {
        #pragma unroll 5
        for (int C = 0; C < 15; ++C) {
            float4 wv0 = *(const float4*)&wsm[R * 15 + C][ec * 8];
            float4 wv1 = *(const float4*)&wsm[R * 15 + C][ec * 8 + 4];
            #pragma unroll
            for (int i = 0; i < 4; ++i) {
                float a0 = ps[0 * PMSZ + pbase[i] - R * PM - C];
                float a1 = ps[1 * PMSZ + pbase[i] + (C - 14) * PM - R];
                float a2 = ps[2 * PMSZ + pbase[i] + (R - 14) * PM + (C - 14)];
                float a3 = ps[3 * PMSZ + pbase[i] - C * PM + (R - 14)];
                acc[i][0] += a0 * wv0.x; acc[i][1] += a0 * wv0.y;
                acc[i][2] += a0 * wv0.z; acc[i][3] += a0 * wv0.w;
                acc[i][4] += a0 * wv1.x; acc[i][5] += a0 * wv1.y;
                acc[i][6] += a0 * wv1.z; acc[i][7] += a0 * wv1.w;
                acc[i][0] += a1 * wv0.x; acc[i][1] += a1 * wv0.y;
                acc[i][2] += a1 * wv0.z; acc[i][3] += a1 * wv0.w;
                acc[i][4] += a1 * wv1.x; acc[i][5] += a1 * wv1.y;
                acc[i][6] += a1 * wv1.z; acc[i][7] += a1 * wv1.w;
                acc[i][0] += a2 * wv0.x; acc[i][1] += a2 * wv0.y;
                acc[i][2] += a2 * wv0.z; acc[i][3] += a2 * wv0.w;
                acc[i][4] += a2 * wv1.x; acc[i][5] += a2 * wv1.y;
                acc[i][6] += a2 * wv1.z; acc[i][7] += a2 * wv1.w;
                acc[i][0] += a3 * wv0.x; acc[i][1] += a3 * wv0.y;
                acc[i][2] += a3 * wv0.z; acc[i][3] += a3 * wv0.w;
                acc[i][4] += a3 * wv1.x; acc[i][5] += a3 * wv1.y;
                acc[i][6] += a3 * wv1.z; acc[i][7] += a3 * wv1.w;
            }
        }
    }

    #pragma unroll
    for (int i = 0; i < 4; ++i) {
        int p = p0 + px + 64 * i;
        if (p < PP) {
            float* dst = reg + ((size_t)b * PP + p) * EE + eq * 32 + ec * 8;
            *(float4*)dst = make_float4(acc[i][0], acc[i][1], acc[i][2], acc[i][3]);
            *(float4*)(dst + 4) = make_float4(acc[i][4], acc[i][5], acc[i][6], acc[i][7]);
        }
    }
}

// ---------------- LSTM: gates GEMM [NROWS x 256]@[256 x 512] + epilogue ------
__global__ __launch_bounds__(256) void k_lstm(const float* __restrict__ regb,
                                              const float* __restrict__ hin,
                                              const float* __restrict__ Wc,
                                              const float* __restrict__ bc,
                                              float* __restrict__ hout,
                                              float* __restrict__ cst) {
    __shared__ float As[64][17];
    __shared__ __align__(16) float Wsm[16][64];
    const int tid = threadIdx.x;
    const int tx = tid & 15;     // col group (jj)
    const int ty = tid >> 4;     // row group
    const int n0 = blockIdx.x * 64;
    const int jp0 = blockIdx.y * 64;

    const int a_nl = tid >> 2;
    const int a_kl = (tid & 3) * 4;
    const int w_kl = tid >> 4;
    const int w_jl = (tid & 15) * 4;

    float acc[4][4] = {{0.f}};

    for (int kt = 0; kt < 16; ++kt) {
        const float* src = (kt < 8) ? regb : hin;
        const int koff = (kt < 8) ? kt * 16 : (kt - 8) * 16;
        int n = n0 + a_nl;
        float4 av = make_float4(0.f, 0.f, 0.f, 0.f);
        if (n < NROWS) av = *(const float4*)(src + (size_t)n * EE + koff + a_kl);
        As[a_nl][a_kl + 0] = av.x; As[a_nl][a_kl + 1] = av.y;
        As[a_nl][a_kl + 2] = av.z; As[a_nl][a_kl + 3] = av.w;
        float4 wv = *(const float4*)(Wc + (size_t)(kt * 16 + w_kl) * 512 + jp0 + w_jl);
        *(float4*)&Wsm[w_kl][w_jl] = wv;
        __syncthreads();
        #pragma unroll
        for (int kl = 0; kl < 16; ++kl) {
            float a0 = As[ty * 4 + 0][kl];
            float a1 = As[ty * 4 + 1][kl];
            float a2 = As[ty * 4 + 2][kl];
            float a3 = As[ty * 4 + 3][kl];
            float4 bv = *(const float4*)&Wsm[kl][tx * 4];
            acc[0][0] += a0 * bv.x; acc[0][1] += a0 * bv.y; acc[0][2] += a0 * bv.z; acc[0][3] += a0 * bv.w;
            acc[1][0] += a1 * bv.x; acc[1][1] += a1 * bv.y; acc[1][2] += a1 * bv.z; acc[1][3] += a1 * bv.w;
            acc[2][0] += a2 * bv.x; acc[2][1] += a2 * bv.y; acc[2][2] += a2 * bv.z; acc[2][3] += a2 * bv.w;
            acc[3][0] += a3 * bv.x; acc[3][1] += a3 * bv.y; acc[3][2] += a3 * bv.z; acc[3][3] += a3 * bv.w;
        }
        __syncthreads();
    }

    const int jj = (jp0 >> 2) + tx;
    float4 bv = *(const float4*)(bc + jj * 4);
    #pragma unroll
    for (int i = 0; i < 4; ++i) {
        int n = n0 + ty * 4 + i;
        if (n >= NROWS) continue;
        float gi = acc[i][0] + bv.x;
        float gf = acc[i][1] + bv.y;
        float gg = acc[i][2] + bv.z;
        float go = acc[i][3] + bv.w;
        size_t off = (size_t)n * EE + jj;
        float cv = cst[off];
        float c2 = sigf(gf) * cv + sigf(gi) * tanhf(gg);
        float h2 = sigf(go) * tanhf(c2);
        cst[off] = c2;
        hout[off] = h2;
    }
}

// ---------------- maps: transpose h[(b,p),e] -> out[b,t,e,p] -----------------
__global__ __launch_bounds__(256) void k_maps(const float* __restrict__ h,
                                              float* __restrict__ out, int t) {
    __shared__ float tile[32][33];
    const int b = blockIdx.z;
    const int p0 = blockIdx.x * 32;
    const int e0 = blockIdx.y * 32;
    const int tx = threadIdx.x & 31;
    const int ty0 = threadIdx.x >> 5;
    for (int ty = ty0; ty < 32; ty += 8) {
        int p = p0 + ty;
        tile[ty][tx] = (p < PP) ? h[((size_t)b * PP + p) * EE + e0 + tx] : 0.f;
    }
    __syncthreads();
    size_t base = MAPS_OFF + ((size_t)(b * NSTEP + t) * EE) * PP;
    for (int ty = ty0; ty < 32; ty += 8) {
        int e = e0 + ty;
        int p = p0 + tx;
        if (p < PP) out[base + (size_t)e * PP + p] = tile[tx][ty];
    }
}

// ---------------- localize: raw[b,o,y,x] = sum_{e,dy,dx} m*w -----------------
// Register-reuse version: thread = (y, 4-wide x-strip, 4-e chunk). Per dy the
// 18 h float4s covering the strip are loaded ONCE into registers, then 15 dx
// taps each read one wave-uniform LDS weight float4 (broadcast) -> 16 FMAs.
// FMA:load ratio 13.3 (was 4). rawp: [eq=32][b][o][729] partials.
__global__ __launch_bounds__(192) void k_localize(const float* __restrict__ h,
                                                  const float* __restrict__ images,
                                                  float* __restrict__ rawp, int t) {
    __shared__ float wsm[225][4];      // 3.6 KB rotated weights, e-chunk of 4
    const int eq = blockIdx.x;         // 0..31
    const int o  = blockIdx.y;
    const int b  = blockIdx.z;
    const int tid = threadIdx.x;

    // stage: wsm[k][j] = img[(eq*4+j)*225 + rotoff(o, k/15, k%15)]
    const float* img = images + ((size_t)(b * TT + t + 1) * EE + eq * 4) * 225;
    for (int i = tid; i < 225 * 4; i += 192) {
        int k = i >> 2, j = i & 3;
        int r = k / 15, c = k - r * 15;
        wsm[k][j] = img[j * 225 + rotoff(o, r, c)];
    }
    __syncthreads();

    const int y  = tid / 7;            // 0..27 (27 invalid)
    const int xs = (tid % 7) * 4;      // x-strip start: 0,4,...,24
    if (y < SS) {
        float a0 = 0.f, a1 = 0.f, a2 = 0.f, a3 = 0.f;
        const float* hb = h + ((size_t)b * PP) * EE + eq * 4;
        for (int dy = 0; dy < 15; ++dy) {
            const float* hrow = hb + (size_t)((y + dy) * MM + xs) * EE;
            float4 hc[18];
            #pragma unroll
            for (int c = 0; c < 18; ++c)
                hc[c] = *(const float4*)(hrow + c * EE);
            #pragma unroll
            for (int dx = 0; dx < 15; ++dx) {
                float4 wv = *(const float4*)&wsm[dy * 15 + dx][0];
                a0 += hc[dx + 0].x * wv.x + hc[dx + 0].y * wv.y + hc[dx + 0].z * wv.z + hc[dx + 0].w * wv.w;
                a1 += hc[dx + 1].x * wv.x + hc[dx + 1].y * wv.y + hc[dx + 1].z * wv.z + hc[dx + 1].w * wv.w;
                a2 += hc[dx + 2].x * wv.x + hc[dx + 2].y * wv.y + hc[dx + 2].z * wv.z + hc[dx + 2].w * wv.w;
                a3 += hc[dx + 3].x * wv.x + hc[dx + 3].y * wv.y + hc[dx + 3].z * wv.z + hc[dx + 3].w * wv.w;
            }
        }
        float* dst = rawp + (((size_t)eq * BB + b) * OO + o) * (SS * SS) + y * SS + xs;
        dst[0] = a0;
        if (xs + 1 < SS) dst[1] = a1;
        if (xs + 2 < SS) dst[2] = a2;
        if (xs + 3 < SS) dst[3] = a3;
    }
}

// ---------------- softmax over (O*27*27) + padded writes + pose update -------
// Sums the 32 e-chunk partials once into LDS, then max/sum/write from LDS.
__global__ __launch_bounds__(256) void k_softmax(const float* __restrict__ rawp,
                                                 float* __restrict__ out,
                                                 float* __restrict__ pose, int t) {
    const int b = blockIdx.x, tid = threadIdx.x;
    const int NTOT = OO * SS * SS;  // 2916
    __shared__ float sv[OO * SS * SS];
    __shared__ float red[256];

    // gather pass: sv[i] = sum over 32 eq partials
    const float* p0 = rawp + (size_t)b * NTOT;
    for (int i = tid; i < NTOT; i += 256) {
        float s = 0.f;
        #pragma unroll
        for (int q = 0; q < NEQ; ++q) s += p0[(size_t)q * BB * NTOT + i];
        sv[i] = s;
    }
    __syncthreads();

    float mx = -3.4e38f;
    for (int i = tid; i < NTOT; i += 256) mx = fmaxf(mx, sv[i]);
    red[tid] = mx; __syncthreads();
    for (int s = 128; s > 0; s >>= 1) {
        if (tid < s) red[tid] = fmaxf(red[tid], red[tid + s]);
        __syncthreads();
    }
    mx = red[0]; __syncthreads();

    float sm = 0.f;
    for (int i = tid; i < NTOT; i += 256) sm += expf(sv[i] - mx);
    red[tid] = sm; __syncthreads();
    for (int s = 128; s > 0; s >>= 1) {
        if (tid < s) red[tid] += red[tid + s];
        __syncthreads();
    }
    const float inv = 1.f / red[0];

    float* rawOut = out + RAWS_OFF + ((size_t)(b * NSTEP + t) * OO) * PP;
    float* spOut  = out + SPS_OFF  + ((size_t)(b * NSTEP + t) * OO) * PP;
    float* pb = pose + (size_t)b * OO * MM * MM;
    for (int i = tid; i < OO * MM * MM; i += 256) {
        int o = i / (MM * MM), rem = i % (MM * MM), yy = rem / MM - VR, xx = rem % MM - VR;
        float rv = 0.f, sv2 = 0.f;
        if ((unsigned)yy < SS && (unsigned)xx < SS) {
            float r = sv[(o * SS + yy) * SS + xx];
            rv = r;
            sv2 = expf(r - mx) * inv;
        }
        rawOut[i] = rv;
        spOut[i] = sv2;
        pb[i] = sv2;
    }
}

extern "C" void kernel_launch(void* const* d_in, const int* in_sizes, int n_in,
                              void* d_out, int out_size, void* d_ws, size_t ws_size,
                              hipStream_t stream) {
    const float* images = (const float*)d_in[0];
    const float* wih    = (const float*)d_in[1];
    const float* whh    = (const float*)d_in[2];
    const float* bih    = (const float*)d_in[3];
    const float* bhh    = (const float*)d_in[4];
    float* out = (float*)d_out;
    float* ws  = (float*)d_ws;

    float* pose = ws;                       // 107584
    float* hA   = pose + 107584;            // 3442688
    float* hB   = hA + 3442688;             // 3442688
    float* cst  = hB + 3442688;             // 3442688
    float* regb = cst + 3442688;            // 3442688
    float* rawp = regb;                     // ALIAS: 1492992 floats inside regb
                                            // (regb dead after k_lstm; rewritten
                                            //  by k_register of the NEXT step,
                                            //  after k_softmax consumed rawp)
    float* Wc   = regb + 3442688;           // 131072
    float* bc   = Wc + 131072;              // 512

    hipMemsetAsync(hA, 0, (size_t)3442688 * 4, stream);
    hipMemsetAsync(cst, 0, (size_t)3442688 * 4, stream);
    k_init<<<421, 256, 0, stream>>>(pose);
    k_prep<<<512, 256, 0, stream>>>(wih, whh, bih, bhh, Wc, bc);

    float* hin = hA;
    float* hout = hB;
    for (int t = 0; t < NSTEP; ++t) {
        k_register<<<dim3(7, 4, BB), 256, 0, stream>>>(images, pose, regb, t);
        k_lstm<<<dim3((NROWS + 63) / 64, 8), 256, 0, stream>>>(regb, hin, Wc, bc, hout, cst);
        k_maps<<<dim3(53, 4, BB), 256, 0, stream>>>(hout, out, t);
        k_localize<<<dim3(NEQ, OO, BB), 192, 0, stream>>>(hout, images, rawp, t);
        k_softmax<<<BB, 256, 0, stream>>>(rawp, out, pose, t);
        float* tmp = hin; hin = hout; hout = tmp;
    }
}

// Round 7
// 7402.130 us; speedup vs baseline: 1.1304x; 1.1304x over previous
//
#include <hip/hip_runtime.h>
#include <math.h>

// Problem constants
#define BB 16      // batch
#define TT 16      // time (input)
#define EE 128     // embed
#define KS 15      // kernel
#define MM 41      // map size
#define OO 4       // orientations
#define VR 7       // view range
#define SS 27      // localize output spatial (41 - 2*7)
#define NSTEP 15
#define PP (MM*MM)          // 1681
#define NROWS (BB*PP)       // 26896

#define RAWS_OFF 0
#define SPS_OFF  1613760            // 16*15*4*1681
#define MAPS_OFF 3227520            // 2*SPS

#define PM 55               // padded map (41 + 2*7)
#define PMSZ (PM*PM)        // 3025

#define NPS 4               // localize partial slots: (eh x dyh)

__device__ __forceinline__ float sigf(float x) { return 1.f / (1.f + expf(-x)); }

// rotate kernel coords (r,c) by o*90deg CCW -> source (ir,ic) in 15x15 image
__device__ __forceinline__ int rotoff(int o, int r, int c) {
    int ir, ic;
    if (o == 0)      { ir = r;      ic = c;      }
    else if (o == 1) { ir = c;      ic = 14 - r; }
    else if (o == 2) { ir = 14 - r; ic = 14 - c; }
    else             { ir = 14 - c; ic = r;      }
    return ir * 15 + ic;
}

// ---------------- pose init: zeros + one-hot at (o=0, 20,20) ----------------
__global__ void k_init(float* __restrict__ pose) {
    int idx = blockIdx.x * 256 + threadIdx.x;
    if (idx < BB * OO * MM * MM) {
        int r = idx % (OO * MM * MM);
        pose[idx] = (r == (20 * MM + 20)) ? 1.f : 0.f;
    }
}

// ---------------- weight prep: Wc[k][jp], jp = jj*4+g, j = g*128+jj ----------
__global__ void k_prep(const float* __restrict__ wih, const float* __restrict__ whh,
                       const float* __restrict__ bih, const float* __restrict__ bhh,
                       float* __restrict__ Wc, float* __restrict__ bc) {
    int idx = blockIdx.x * 256 + threadIdx.x;   // [0, 256*512)
    int k = idx >> 9, jp = idx & 511;
    int jj = jp >> 2, g = jp & 3, j = g * 128 + jj;
    Wc[idx] = (k < 128) ? wih[j * 128 + k] : whh[j * 128 + (k - 128)];
    if (idx < 512) {
        int jj2 = idx >> 2, g2 = idx & 3, j2 = g2 * 128 + jj2;
        bc[idx] = bih[j2] + bhh[j2];
    }
}

// ---------------- register: conv-transpose of pose with rotated images -------
// reg[b, p=(y,x), e] = sum_{o,dy,dx} pose[b,o,y+7-dy,x+7-dx] * rot_o(img[b,t])[e,dy,dx]
// Reformulated over IMG taps (R,C): weight read once, 4 inverse-rotated pose taps.
// Padded pose ps[r][c] = pose[r-7][c-7]; pbase = (y+14)*PM + (x+14).
__global__ __launch_bounds__(256) void k_register(const float* __restrict__ images,
                                                  const float* __restrict__ pose,
                                                  float* __restrict__ reg, int t) {
    __shared__ float ps[OO * PMSZ];      // 48.4 KB padded pose
    __shared__ float wsm[225][36];       // 32.4 KB img quarter, transposed (+pad)
    const int p0 = blockIdx.x * 256;
    const int eq = blockIdx.y;           // e quarter: 32 e
    const int b  = blockIdx.z;
    const int tid = threadIdx.x;

    // stage padded pose (zeros in halo)
    for (int i = tid; i < OO * PMSZ; i += 256) {
        int o = i / PMSZ, rem = i % PMSZ, r = rem / PM, c = rem % PM;
        float v = 0.f;
        if (r >= VR && r < VR + MM && c >= VR && c < VR + MM)
            v = pose[(((size_t)b * OO + o) * MM + (r - VR)) * MM + (c - VR)];
        ps[i] = v;
    }
    // stage img quarter transposed: wsm[k][e] = img[e][k]
    const float* img = images + ((size_t)(b * TT + t) * EE + eq * 32) * 225;
    for (int i = tid; i < 32 * 225; i += 256) {
        int e = i / 225, k = i - e * 225;
        wsm[k][e] = img[e * 225 + k];
    }
    __syncthreads();

    const int px = tid & 63;
    const int ec = tid >> 6;             // 0..3, uniform per wave -> wsm broadcast
    int pbase[4];
    #pragma unroll
    for (int i = 0; i < 4; ++i) {
        int p = p0 + px + 64 * i;
        int pc = (p < PP) ? p : 0;
        int y = pc / MM, x = pc - y * MM;
        pbase[i] = (y + 2 * VR) * PM + (x + 2 * VR);
    }

    float acc[4][8];
    #pragma unroll
    for (int i = 0; i < 4; ++i)
        #pragma unroll
        for (int j = 0; j < 8; ++j) acc[i][j] = 0.f;

    for (int R = 0; R < 15; ++R) {
        #pragma unroll 5
        for (int C = 0; C < 15; ++C) {
            float4 wv0 = *(const float4*)&wsm[R * 15 + C][ec * 8];
            float4 wv1 = *(const float4*)&wsm[R * 15 + C][ec * 8 + 4];
            #pragma unroll
            for (int i = 0; i < 4; ++i) {
                float a0 = ps[0 * PMSZ + pbase[i] - R * PM - C];
                float a1 = ps[1 * PMSZ + pbase[i] + (C - 14) * PM - R];
                float a2 = ps[2 * PMSZ + pbase[i] + (R - 14) * PM + (C - 14)];
                float a3 = ps[3 * PMSZ + pbase[i] - C * PM + (R - 14)];
                acc[i][0] += a0 * wv0.x; acc[i][1] += a0 * wv0.y;
                acc[i][2] += a0 * wv0.z; acc[i][3] += a0 * wv0.w;
                acc[i][4] += a0 * wv1.x; acc[i][5] += a0 * wv1.y;
                acc[i][6] += a0 * wv1.z; acc[i][7] += a0 * wv1.w;
                acc[i][0] += a1 * wv0.x; acc[i][1] += a1 * wv0.y;
                acc[i][2] += a1 * wv0.z; acc[i][3] += a1 * wv0.w;
                acc[i][4] += a1 * wv1.x; acc[i][5] += a1 * wv1.y;
                acc[i][6] += a1 * wv1.z; acc[i][7] += a1 * wv1.w;
                acc[i][0] += a2 * wv0.x; acc[i][1] += a2 * wv0.y;
                acc[i][2] += a2 * wv0.z; acc[i][3] += a2 * wv0.w;
                acc[i][4] += a2 * wv1.x; acc[i][5] += a2 * wv1.y;
                acc[i][6] += a2 * wv1.z; acc[i][7] += a2 * wv1.w;
                acc[i][0] += a3 * wv0.x; acc[i][1] += a3 * wv0.y;
                acc[i][2] += a3 * wv0.z; acc[i][3] += a3 * wv0.w;
                acc[i][4] += a3 * wv1.x; acc[i][5] += a3 * wv1.y;
                acc[i][6] += a3 * wv1.z; acc[i][7] += a3 * wv1.w;
            }
        }
    }

    #pragma unroll
    for (int i = 0; i < 4; ++i) {
        int p = p0 + px + 64 * i;
        if (p < PP) {
            float* dst = reg + ((size_t)b * PP + p) * EE + eq * 32 + ec * 8;
            *(float4*)dst = make_float4(acc[i][0], acc[i][1], acc[i][2], acc[i][3]);
            *(float4*)(dst + 4) = make_float4(acc[i][4], acc[i][5], acc[i][6], acc[i][7]);
        }
    }
}

// ---------------- LSTM: gates GEMM [NROWS x 256]@[256 x 512] + epilogue ------
__global__ __launch_bounds__(256) void k_lstm(const float* __restrict__ regb,
                                              const float* __restrict__ hin,
                                              const float* __restrict__ Wc,
                                              const float* __restrict__ bc,
                                              float* __restrict__ hout,
                                              float* __restrict__ cst) {
    __shared__ float As[64][17];
    __shared__ __align__(16) float Wsm[16][64];
    const int tid = threadIdx.x;
    const int tx = tid & 15;     // col group (jj)
    const int ty = tid >> 4;     // row group
    const int n0 = blockIdx.x * 64;
    const int jp0 = blockIdx.y * 64;

    const int a_nl = tid >> 2;
    const int a_kl = (tid & 3) * 4;
    const int w_kl = tid >> 4;
    const int w_jl = (tid & 15) * 4;

    float acc[4][4] = {{0.f}};

    for (int kt = 0; kt < 16; ++kt) {
        const float* src = (kt < 8) ? regb : hin;
        const int koff = (kt < 8) ? kt * 16 : (kt - 8) * 16;
        int n = n0 + a_nl;
        float4 av = make_float4(0.f, 0.f, 0.f, 0.f);
        if (n < NROWS) av = *(const float4*)(src + (size_t)n * EE + koff + a_kl);
        As[a_nl][a_kl + 0] = av.x; As[a_nl][a_kl + 1] = av.y;
        As[a_nl][a_kl + 2] = av.z; As[a_nl][a_kl + 3] = av.w;
        float4 wv = *(const float4*)(Wc + (size_t)(kt * 16 + w_kl) * 512 + jp0 + w_jl);
        *(float4*)&Wsm[w_kl][w_jl] = wv;
        __syncthreads();
        #pragma unroll
        for (int kl = 0; kl < 16; ++kl) {
            float a0 = As[ty * 4 + 0][kl];
            float a1 = As[ty * 4 + 1][kl];
            float a2 = As[ty * 4 + 2][kl];
            float a3 = As[ty * 4 + 3][kl];
            float4 bv = *(const float4*)&Wsm[kl][tx * 4];
            acc[0][0] += a0 * bv.x; acc[0][1] += a0 * bv.y; acc[0][2] += a0 * bv.z; acc[0][3] += a0 * bv.w;
            acc[1][0] += a1 * bv.x; acc[1][1] += a1 * bv.y; acc[1][2] += a1 * bv.z; acc[1][3] += a1 * bv.w;
            acc[2][0] += a2 * bv.x; acc[2][1] += a2 * bv.y; acc[2][2] += a2 * bv.z; acc[2][3] += a2 * bv.w;
            acc[3][0] += a3 * bv.x; acc[3][1] += a3 * bv.y; acc[3][2] += a3 * bv.z; acc[3][3] += a3 * bv.w;
        }
        __syncthreads();
    }

    const int jj = (jp0 >> 2) + tx;
    float4 bv = *(const float4*)(bc + jj * 4);
    #pragma unroll
    for (int i = 0; i < 4; ++i) {
        int n = n0 + ty * 4 + i;
        if (n >= NROWS) continue;
        float gi = acc[i][0] + bv.x;
        float gf = acc[i][1] + bv.y;
        float gg = acc[i][2] + bv.z;
        float go = acc[i][3] + bv.w;
        size_t off = (size_t)n * EE + jj;
        float cv = cst[off];
        float c2 = sigf(gf) * cv + sigf(gi) * tanhf(gg);
        float h2 = sigf(go) * tanhf(c2);
        cst[off] = c2;
        hout[off] = h2;
    }
}

// ---------------- maps: transpose h[(b,p),e] -> out[b,t,e,p] -----------------
__global__ __launch_bounds__(256) void k_maps(const float* __restrict__ h,
                                              float* __restrict__ out, int t) {
    __shared__ float tile[32][33];
    const int b = blockIdx.z;
    const int p0 = blockIdx.x * 32;
    const int e0 = blockIdx.y * 32;
    const int tx = threadIdx.x & 31;
    const int ty0 = threadIdx.x >> 5;
    for (int ty = ty0; ty < 32; ty += 8) {
        int p = p0 + ty;
        tile[ty][tx] = (p < PP) ? h[((size_t)b * PP + p) * EE + e0 + tx] : 0.f;
    }
    __syncthreads();
    size_t base = MAPS_OFF + ((size_t)(b * NSTEP + t) * EE) * PP;
    for (int ty = ty0; ty < 32; ty += 8) {
        int e = e0 + ty;
        int p = p0 + tx;
        if (p < PP) out[base + (size_t)e * PP + p] = tile[tx][ty];
    }
}

// ---------------- wprep: wT[b][o][tap][e] = rot_o(img[b,t+1])[e][tap] --------
// LDS-staged; both global read and write fully coalesced.
__global__ __launch_bounds__(256) void k_wprep(const float* __restrict__ images,
                                               float* __restrict__ wT, int t) {
    __shared__ float img_s[64][225];   // 57.6 KB
    const int eh = blockIdx.x;   // 0..1
    const int o  = blockIdx.y;
    const int b  = blockIdx.z;
    const int tid = threadIdx.x;
    const float* img = images + ((size_t)(b * TT + t + 1) * EE + eh * 64) * 225;
    for (int i = tid; i < 64 * 225; i += 256)
        img_s[i / 225][i % 225] = img[i];   // contiguous copy
    __syncthreads();
    float* w = wT + ((size_t)(b * OO + o) * 225) * EE + eh * 64;
    for (int j = tid; j < 225 * 64; j += 256) {
        int tap = j >> 6, el = j & 63;
        int r = tap / 15, c = tap - r * 15;
        w[(size_t)tap * EE + el] = img_s[el][rotoff(o, r, c)];
    }
}

// ---------------- localize: lane = e-channel; coalesced, register h-row ------
// wave = (b, y, e-half, dy-half). Per dy: 41 coalesced h loads into hrow[],
// then 4 o x 15 dx x (1 coalesced w load + 27 FMA). shfl_xor-reduce over e.
// rawp: [ps=4][b][o][729] partials.
__global__ __launch_bounds__(256, 2) void k_localize(const float* __restrict__ h,
                                                     const float* __restrict__ wT,
                                                     float* __restrict__ rawp) {
    const int y  = blockIdx.x;          // 0..26
    const int b  = blockIdx.y;          // 0..15
    const int ps = threadIdx.x >> 6;    // wave 0..3
    const int lane = threadIdx.x & 63;
    const int eh  = ps & 1;
    const int dyh = ps >> 1;
    const int e   = eh * 64 + lane;
    const int dy0 = dyh ? 8 : 0;
    const int dy1 = dyh ? 15 : 8;

    float acc[OO][SS];
    #pragma unroll
    for (int o = 0; o < OO; ++o)
        #pragma unroll
        for (int x = 0; x < SS; ++x) acc[o][x] = 0.f;

    const float* hb = h + (size_t)b * PP * EE + e;
    const float* wb = wT + ((size_t)b * OO * 225) * EE + e;

    for (int dy = dy0; dy < dy1; ++dy) {
        float hrow[MM];
        const float* hr = hb + (size_t)((y + dy) * MM) * EE;
        #pragma unroll
        for (int c = 0; c < MM; ++c) hrow[c] = hr[(size_t)c * EE];
        #pragma unroll
        for (int o = 0; o < OO; ++o) {
            const float* wo = wb + ((size_t)o * 225 + dy * 15) * EE;
            #pragma unroll
            for (int dx = 0; dx < 15; ++dx) {
                float wv = wo[(size_t)dx * EE];
                #pragma unroll
                for (int x = 0; x < SS; ++x)
                    acc[o][x] += hrow[x + dx] * wv;
            }
        }
    }

    #pragma unroll
    for (int o = 0; o < OO; ++o)
        #pragma unroll
        for (int x = 0; x < SS; ++x) {
            float v = acc[o][x];
            v += __shfl_xor(v, 1);  v += __shfl_xor(v, 2);  v += __shfl_xor(v, 4);
            v += __shfl_xor(v, 8);  v += __shfl_xor(v, 16); v += __shfl_xor(v, 32);
            if (lane == 0)
                rawp[(((size_t)ps * BB + b) * OO + o) * (SS * SS) + y * SS + x] = v;
        }
}

// ---------------- softmax over (O*27*27) + padded writes + pose update -------
// Sums the 4 partial slots once into LDS, then max/sum/write from LDS.
__global__ __launch_bounds__(256) void k_softmax(const float* __restrict__ rawp,
                                                 float* __restrict__ out,
                                                 float* __restrict__ pose, int t) {
    const int b = blockIdx.x, tid = threadIdx.x;
    const int NTOT = OO * SS * SS;  // 2916
    __shared__ float sv[OO * SS * SS];
    __shared__ float red[256];

    const float* p0 = rawp + (size_t)b * NTOT;
    for (int i = tid; i < NTOT; i += 256) {
        float s = 0.f;
        #pragma unroll
        for (int q = 0; q < NPS; ++q) s += p0[(size_t)q * BB * NTOT + i];
        sv[i] = s;
    }
    __syncthreads();

    float mx = -3.4e38f;
    for (int i = tid; i < NTOT; i += 256) mx = fmaxf(mx, sv[i]);
    red[tid] = mx; __syncthreads();
    for (int s = 128; s > 0; s >>= 1) {
        if (tid < s) red[tid] = fmaxf(red[tid], red[tid + s]);
        __syncthreads();
    }
    mx = red[0]; __syncthreads();

    float sm = 0.f;
    for (int i = tid; i < NTOT; i += 256) sm += expf(sv[i] - mx);
    red[tid] = sm; __syncthreads();
    for (int s = 128; s > 0; s >>= 1) {
        if (tid < s) red[tid] += red[tid + s];
        __syncthreads();
    }
    const float inv = 1.f / red[0];

    float* rawOut = out + RAWS_OFF + ((size_t)(b * NSTEP + t) * OO) * PP;
    float* spOut  = out + SPS_OFF  + ((size_t)(b * NSTEP + t) * OO) * PP;
    float* pb = pose + (size_t)b * OO * MM * MM;
    for (int i = tid; i < OO * MM * MM; i += 256) {
        int o = i / (MM * MM), rem = i % (MM * MM), yy = rem / MM - VR, xx = rem % MM - VR;
        float rv = 0.f, sv2 = 0.f;
        if ((unsigned)yy < SS && (unsigned)xx < SS) {
            float r = sv[(o * SS + yy) * SS + xx];
            rv = r;
            sv2 = expf(r - mx) * inv;
        }
        rawOut[i] = rv;
        spOut[i] = sv2;
        pb[i] = sv2;
    }
}

extern "C" void kernel_launch(void* const* d_in, const int* in_sizes, int n_in,
                              void* d_out, int out_size, void* d_ws, size_t ws_size,
                              hipStream_t stream) {
    const float* images = (const float*)d_in[0];
    const float* wih    = (const float*)d_in[1];
    const float* whh    = (const float*)d_in[2];
    const float* bih    = (const float*)d_in[3];
    const float* bhh    = (const float*)d_in[4];
    float* out = (float*)d_out;
    float* ws  = (float*)d_ws;

    float* pose = ws;                       // 107584
    float* hA   = pose + 107584;            // 3442688
    float* hB   = hA + 3442688;             // 3442688
    float* cst  = hB + 3442688;             // 3442688
    float* regb = cst + 3442688;            // 3442688
    // Aliases inside regb (dead between k_lstm of step t and k_register of t+1):
    //   rawp = regb[0 : 186624]          (4 x 16 x 4 x 729)
    //   wT   = regb[262144 : 262144+1843200]  (16 x 4 x 225 x 128)
    // Per-step order: k_register(W regb) -> k_lstm(R regb) -> k_wprep(W wT)
    //                 -> k_localize(R wT, W rawp) -> k_softmax(R rawp). Safe.
    float* rawp = regb;
    float* wT   = regb + 262144;
    float* Wc   = regb + 3442688;           // 131072
    float* bc   = Wc + 131072;              // 512

    hipMemsetAsync(hA, 0, (size_t)3442688 * 4, stream);
    hipMemsetAsync(cst, 0, (size_t)3442688 * 4, stream);
    k_init<<<421, 256, 0, stream>>>(pose);
    k_prep<<<512, 256, 0, stream>>>(wih, whh, bih, bhh, Wc, bc);

    float* hin = hA;
    float* hout = hB;
    for (int t = 0; t < NSTEP; ++t) {
        k_register<<<dim3(7, 4, BB), 256, 0, stream>>>(images, pose, regb, t);
        k_lstm<<<dim3((NROWS + 63) / 64, 8), 256, 0, stream>>>(regb, hin, Wc, bc, hout, cst);
        k_wprep<<<dim3(2, OO, BB), 256, 0, stream>>>(images, wT, t);
        k_maps<<<dim3(53, 4, BB), 256, 0, stream>>>(hout, out, t);
        k_localize<<<dim3(SS, BB), 256, 0, stream>>>(hout, wT, rawp);
        k_softmax<<<BB, 256, 0, stream>>>(rawp, out, pose, t);
        float* tmp = hin; hin = hout; hout = tmp;
    }
}

// Round 8
// 4721.803 us; speedup vs baseline: 1.7721x; 1.5676x over previous
//
#include <hip/hip_runtime.h>
#include <math.h>

// Problem constants
#define BB 16      // batch
#define TT 16      // time (input)
#define EE 128     // embed
#define KS 15      // kernel
#define MM 41      // map size
#define OO 4       // orientations
#define VR 7       // view range
#define SS 27      // localize output spatial (41 - 2*7)
#define NSTEP 15
#define PP (MM*MM)          // 1681
#define NROWS (BB*PP)       // 26896

#define RAWS_OFF 0
#define SPS_OFF  1613760            // 16*15*4*1681
#define MAPS_OFF 3227520            // 2*SPS

#define PM 55               // padded map (41 + 2*7)
#define PMSZ (PM*PM)        // 3025

#define NPS 4               // localize partial slots: (eh x dyh)

__device__ __forceinline__ float sigf(float x) { return 1.f / (1.f + expf(-x)); }

// rotate kernel coords (r,c) by o*90deg CCW -> source (ir,ic) in 15x15 image
__device__ __forceinline__ int rotoff(int o, int r, int c) {
    int ir, ic;
    if (o == 0)      { ir = r;      ic = c;      }
    else if (o == 1) { ir = c;      ic = 14 - r; }
    else if (o == 2) { ir = 14 - r; ic = 14 - c; }
    else             { ir = 14 - c; ic = r;      }
    return ir * 15 + ic;
}

// ---------------- pose init: zeros + one-hot at (o=0, 20,20) ----------------
__global__ void k_init(float* __restrict__ pose) {
    int idx = blockIdx.x * 256 + threadIdx.x;
    if (idx < BB * OO * MM * MM) {
        int r = idx % (OO * MM * MM);
        pose[idx] = (r == (20 * MM + 20)) ? 1.f : 0.f;
    }
}

// ---------------- weight prep: Wc[k][jp], jp = jj*4+g, j = g*128+jj ----------
__global__ void k_prep(const float* __restrict__ wih, const float* __restrict__ whh,
                       const float* __restrict__ bih, const float* __restrict__ bhh,
                       float* __restrict__ Wc, float* __restrict__ bc) {
    int idx = blockIdx.x * 256 + threadIdx.x;   // [0, 256*512)
    int k = idx >> 9, jp = idx & 511;
    int jj = jp >> 2, g = jp & 3, j = g * 128 + jj;
    Wc[idx] = (k < 128) ? wih[j * 128 + k] : whh[j * 128 + (k - 128)];
    if (idx < 512) {
        int jj2 = idx >> 2, g2 = idx & 3, j2 = g2 * 128 + jj2;
        bc[idx] = bih[j2] + bhh[j2];
    }
}

// ---------------- register: conv-transpose of pose with rotated images -------
// reg[b, p=(y,x), e] = sum_{o,dy,dx} pose[b,o,y+7-dy,x+7-dx] * rot_o(img[b,t])[e,dy,dx]
// Reformulated over IMG taps (R,C): weight read once, 4 inverse-rotated pose taps.
// Padded pose ps[r][c] = pose[r-7][c-7]; pbase = (y+14)*PM + (x+14).
__global__ __launch_bounds__(256) void k_register(const float* __restrict__ images,
                                                  const float* __restrict__ pose,
                                                  float* __restrict__ reg, int t) {
    __shared__ float ps[OO * PMSZ];      // 48.4 KB padded pose
    __shared__ float wsm[225][36];       // 32.4 KB img quarter, transposed (+pad)
    const int p0 = blockIdx.x * 256;
    const int eq = blockIdx.y;           // e quarter: 32 e
    const int b  = blockIdx.z;
    const int tid = threadIdx.x;

    // stage padded pose (zeros in halo)
    for (int i = tid; i < OO * PMSZ; i += 256) {
        int o = i / PMSZ, rem = i % PMSZ, r = rem / PM, c = rem % PM;
        float v = 0.f;
        if (r >= VR && r < VR + MM && c >= VR && c < VR + MM)
            v = pose[(((size_t)b * OO + o) * MM + (r - VR)) * MM + (c - VR)];
        ps[i] = v;
    }
    // stage img quarter transposed: wsm[k][e] = img[e][k]
    const float* img = images + ((size_t)(b * TT + t) * EE + eq * 32) * 225;
    for (int i = tid; i < 32 * 225; i += 256) {
        int e = i / 225, k = i - e * 225;
        wsm[k][e] = img[e * 225 + k];
    }
    __syncthreads();

    const int px = tid & 63;
    const int ec = tid >> 6;             // 0..3, uniform per wave -> wsm broadcast
    int pbase[4];
    #pragma unroll
    for (int i = 0; i < 4; ++i) {
        int p = p0 + px + 64 * i;
        int pc = (p < PP) ? p : 0;
        int y = pc / MM, x = pc - y * MM;
        pbase[i] = (y + 2 * VR) * PM + (x + 2 * VR);
    }

    float acc[4][8];
    #pragma unroll
    for (int i = 0; i < 4; ++i)
        #pragma unroll
        for (int j = 0; j < 8; ++j) acc[i][j] = 0.f;

    for (int R = 0; R < 15; ++R) {
        #pragma unroll 5
        for (int C = 0; C < 15; ++C) {
            float4 wv0 = *(const float4*)&wsm[R * 15 + C][ec * 8];
            float4 wv1 = *(const float4*)&wsm[R * 15 + C][ec * 8 + 4];
            #pragma unroll
            for (int i = 0; i < 4; ++i) {
                float a0 = ps[0 * PMSZ + pbase[i] - R * PM - C];
                float a1 = ps[1 * PMSZ + pbase[i] + (C - 14) * PM - R];
                float a2 = ps[2 * PMSZ + pbase[i] + (R - 14) * PM + (C - 14)];
                float a3 = ps[3 * PMSZ + pbase[i] - C * PM + (R - 14)];
                acc[i][0] += a0 * wv0.x; acc[i][1] += a0 * wv0.y;
                acc[i][2] += a0 * wv0.z; acc[i][3] += a0 * wv0.w;
                acc[i][4] += a0 * wv1.x; acc[i][5] += a0 * wv1.y;
                acc[i][6] += a0 * wv1.z; acc[i][7] += a0 * wv1.w;
                acc[i][0] += a1 * wv0.x; acc[i][1] += a1 * wv0.y;
                acc[i][2] += a1 * wv0.z; acc[i][3] += a1 * wv0.w;
                acc[i][4] += a1 * wv1.x; acc[i][5] += a1 * wv1.y;
                acc[i][6] += a1 * wv1.z; acc[i][7] += a1 * wv1.w;
                acc[i][0] += a2 * wv0.x; acc[i][1] += a2 * wv0.y;
                acc[i][2] += a2 * wv0.z; acc[i][3] += a2 * wv0.w;
                acc[i][4] += a2 * wv1.x; acc[i][5] += a2 * wv1.y;
                acc[i][6] += a2 * wv1.z; acc[i][7] += a2 * wv1.w;
                acc[i][0] += a3 * wv0.x; acc[i][1] += a3 * wv0.y;
                acc[i][2] += a3 * wv0.z; acc[i][3] += a3 * wv0.w;
                acc[i][4] += a3 * wv1.x; acc[i][5] += a3 * wv1.y;
                acc[i][6] += a3 * wv1.z; acc[i][7] += a3 * wv1.w;
            }
        }
    }

    #pragma unroll
    for (int i = 0; i < 4; ++i) {
        int p = p0 + px + 64 * i;
        if (p < PP) {
            float* dst = reg + ((size_t)b * PP + p) * EE + eq * 32 + ec * 8;
            *(float4*)dst = make_float4(acc[i][0], acc[i][1], acc[i][2], acc[i][3]);
            *(float4*)(dst + 4) = make_float4(acc[i][4], acc[i][5], acc[i][6], acc[i][7]);
        }
    }
}

// ---------------- LSTM: gates GEMM [NROWS x 256]@[256 x 512] + epilogue ------
__global__ __launch_bounds__(256) void k_lstm(const float* __restrict__ regb,
                                              const float* __restrict__ hin,
                                              const float* __restrict__ Wc,
                                              const float* __restrict__ bc,
                                              float* __restrict__ hout,
                                              float* __restrict__ cst) {
    __shared__ float As[64][17];
    __shared__ __align__(16) float Wsm[16][64];
    const int tid = threadIdx.x;
    const int tx = tid & 15;     // col group (jj)
    const int ty = tid >> 4;     // row group
    const int n0 = blockIdx.x * 64;
    const int jp0 = blockIdx.y * 64;

    const int a_nl = tid >> 2;
    const int a_kl = (tid & 3) * 4;
    const int w_kl = tid >> 4;
    const int w_jl = (tid & 15) * 4;

    float acc[4][4] = {{0.f}};

    for (int kt = 0; kt < 16; ++kt) {
        const float* src = (kt < 8) ? regb : hin;
        const int koff = (kt < 8) ? kt * 16 : (kt - 8) * 16;
        int n = n0 + a_nl;
        float4 av = make_float4(0.f, 0.f, 0.f, 0.f);
        if (n < NROWS) av = *(const float4*)(src + (size_t)n * EE + koff + a_kl);
        As[a_nl][a_kl + 0] = av.x; As[a_nl][a_kl + 1] = av.y;
        As[a_nl][a_kl + 2] = av.z; As[a_nl][a_kl + 3] = av.w;
        float4 wv = *(const float4*)(Wc + (size_t)(kt * 16 + w_kl) * 512 + jp0 + w_jl);
        *(float4*)&Wsm[w_kl][w_jl] = wv;
        __syncthreads();
        #pragma unroll
        for (int kl = 0; kl < 16; ++kl) {
            float a0 = As[ty * 4 + 0][kl];
            float a1 = As[ty * 4 + 1][kl];
            float a2 = As[ty * 4 + 2][kl];
            float a3 = As[ty * 4 + 3][kl];
            float4 bv = *(const float4*)&Wsm[kl][tx * 4];
            acc[0][0] += a0 * bv.x; acc[0][1] += a0 * bv.y; acc[0][2] += a0 * bv.z; acc[0][3] += a0 * bv.w;
            acc[1][0] += a1 * bv.x; acc[1][1] += a1 * bv.y; acc[1][2] += a1 * bv.z; acc[1][3] += a1 * bv.w;
            acc[2][0] += a2 * bv.x; acc[2][1] += a2 * bv.y; acc[2][2] += a2 * bv.z; acc[2][3] += a2 * bv.w;
            acc[3][0] += a3 * bv.x; acc[3][1] += a3 * bv.y; acc[3][2] += a3 * bv.z; acc[3][3] += a3 * bv.w;
        }
        __syncthreads();
    }

    const int jj = (jp0 >> 2) + tx;
    float4 bv = *(const float4*)(bc + jj * 4);
    #pragma unroll
    for (int i = 0; i < 4; ++i) {
        int n = n0 + ty * 4 + i;
        if (n >= NROWS) continue;
        float gi = acc[i][0] + bv.x;
        float gf = acc[i][1] + bv.y;
        float gg = acc[i][2] + bv.z;
        float go = acc[i][3] + bv.w;
        size_t off = (size_t)n * EE + jj;
        float cv = cst[off];
        float c2 = sigf(gf) * cv + sigf(gi) * tanhf(gg);
        float h2 = sigf(go) * tanhf(c2);
        cst[off] = c2;
        hout[off] = h2;
    }
}

// ---------------- maps: transpose h[(b,p),e] -> out[b,t,e,p] -----------------
__global__ __launch_bounds__(256) void k_maps(const float* __restrict__ h,
                                              float* __restrict__ out, int t) {
    __shared__ float tile[32][33];
    const int b = blockIdx.z;
    const int p0 = blockIdx.x * 32;
    const int e0 = blockIdx.y * 32;
    const int tx = threadIdx.x & 31;
    const int ty0 = threadIdx.x >> 5;
    for (int ty = ty0; ty < 32; ty += 8) {
        int p = p0 + ty;
        tile[ty][tx] = (p < PP) ? h[((size_t)b * PP + p) * EE + e0 + tx] : 0.f;
    }
    __syncthreads();
    size_t base = MAPS_OFF + ((size_t)(b * NSTEP + t) * EE) * PP;
    for (int ty = ty0; ty < 32; ty += 8) {
        int e = e0 + ty;
        int p = p0 + tx;
        if (p < PP) out[base + (size_t)e * PP + p] = tile[tx][ty];
    }
}

// ---------------- wprep: wT[b][o][tap][e] = rot_o(img[b,t+1])[e][tap] --------
// LDS-staged; both global read and write fully coalesced.
__global__ __launch_bounds__(256) void k_wprep(const float* __restrict__ images,
                                               float* __restrict__ wT, int t) {
    __shared__ float img_s[64][225];   // 57.6 KB
    const int eh = blockIdx.x;   // 0..1
    const int o  = blockIdx.y;
    const int b  = blockIdx.z;
    const int tid = threadIdx.x;
    const float* img = images + ((size_t)(b * TT + t + 1) * EE + eh * 64) * 225;
    for (int i = tid; i < 64 * 225; i += 256)
        img_s[i / 225][i % 225] = img[i];   // contiguous copy
    __syncthreads();
    float* w = wT + ((size_t)(b * OO + o) * 225) * EE + eh * 64;
    for (int j = tid; j < 225 * 64; j += 256) {
        int tap = j >> 6, el = j & 63;
        int r = tap / 15, c = tap - r * 15;
        w[(size_t)tap * EE + el] = img_s[el][rotoff(o, r, c)];
    }
}

// ---------------- localize: lane = e-channel; o moved to grid (no spills) ----
// block = (y, b, o); 4 waves = (eh, dyh). Per dy: 41 coalesced h loads into
// registers, then 15 dx x (1 coalesced w load + 27 FMA). shfl-reduce over e.
// Per-thread state: acc[27] + hrow[41] ~ 90 VGPR -> no scratch.
// rawp: [ps=4][b][o][729] partials (ps = wave id).
__global__ __launch_bounds__(256) void k_localize(const float* __restrict__ h,
                                                  const float* __restrict__ wT,
                                                  float* __restrict__ rawp) {
    const int y  = blockIdx.x;          // 0..26
    const int b  = blockIdx.y;          // 0..15
    const int o  = blockIdx.z;          // 0..3
    const int ps = threadIdx.x >> 6;    // wave 0..3
    const int lane = threadIdx.x & 63;
    const int eh  = ps & 1;
    const int dyh = ps >> 1;
    const int e   = eh * 64 + lane;
    const int dy0 = dyh ? 8 : 0;
    const int dy1 = dyh ? 15 : 8;

    float acc[SS];
    #pragma unroll
    for (int x = 0; x < SS; ++x) acc[x] = 0.f;

    const float* hb = h + (size_t)b * PP * EE + e;
    const float* wo = wT + (((size_t)b * OO + o) * 225) * EE + e;

    for (int dy = dy0; dy < dy1; ++dy) {
        float hrow[MM];
        const float* hr = hb + (size_t)((y + dy) * MM) * EE;
        #pragma unroll
        for (int c = 0; c < MM; ++c) hrow[c] = hr[(size_t)c * EE];
        const float* wd = wo + (size_t)(dy * 15) * EE;
        #pragma unroll
        for (int dx = 0; dx < 15; ++dx) {
            float wv = wd[(size_t)dx * EE];
            #pragma unroll
            for (int x = 0; x < SS; ++x)
                acc[x] += hrow[x + dx] * wv;
        }
    }

    #pragma unroll
    for (int x = 0; x < SS; ++x) {
        float v = acc[x];
        v += __shfl_xor(v, 1);  v += __shfl_xor(v, 2);  v += __shfl_xor(v, 4);
        v += __shfl_xor(v, 8);  v += __shfl_xor(v, 16); v += __shfl_xor(v, 32);
        if (lane == 0)
            rawp[(((size_t)ps * BB + b) * OO + o) * (SS * SS) + y * SS + x] = v;
    }
}

// ---------------- softmax over (O*27*27) + padded writes + pose update -------
// Sums the 4 partial slots once into LDS, then max/sum/write from LDS.
__global__ __launch_bounds__(256) void k_softmax(const float* __restrict__ rawp,
                                                 float* __restrict__ out,
                                                 float* __restrict__ pose, int t) {
    const int b = blockIdx.x, tid = threadIdx.x;
    const int NTOT = OO * SS * SS;  // 2916
    __shared__ float sv[OO * SS * SS];
    __shared__ float red[256];

    const float* p0 = rawp + (size_t)b * NTOT;
    for (int i = tid; i < NTOT; i += 256) {
        float s = 0.f;
        #pragma unroll
        for (int q = 0; q < NPS; ++q) s += p0[(size_t)q * BB * NTOT + i];
        sv[i] = s;
    }
    __syncthreads();

    float mx = -3.4e38f;
    for (int i = tid; i < NTOT; i += 256) mx = fmaxf(mx, sv[i]);
    red[tid] = mx; __syncthreads();
    for (int s = 128; s > 0; s >>= 1) {
        if (tid < s) red[tid] = fmaxf(red[tid], red[tid + s]);
        __syncthreads();
    }
    mx = red[0]; __syncthreads();

    float sm = 0.f;
    for (int i = tid; i < NTOT; i += 256) sm += expf(sv[i] - mx);
    red[tid] = sm; __syncthreads();
    for (int s = 128; s > 0; s >>= 1) {
        if (tid < s) red[tid] += red[tid + s];
        __syncthreads();
    }
    const float inv = 1.f / red[0];

    float* rawOut = out + RAWS_OFF + ((size_t)(b * NSTEP + t) * OO) * PP;
    float* spOut  = out + SPS_OFF  + ((size_t)(b * NSTEP + t) * OO) * PP;
    float* pb = pose + (size_t)b * OO * MM * MM;
    for (int i = tid; i < OO * MM * MM; i += 256) {
        int o = i / (MM * MM), rem = i % (MM * MM), yy = rem / MM - VR, xx = rem % MM - VR;
        float rv = 0.f, sv2 = 0.f;
        if ((unsigned)yy < SS && (unsigned)xx < SS) {
            float r = sv[(o * SS + yy) * SS + xx];
            rv = r;
            sv2 = expf(r - mx) * inv;
        }
        rawOut[i] = rv;
        spOut[i] = sv2;
        pb[i] = sv2;
    }
}

extern "C" void kernel_launch(void* const* d_in, const int* in_sizes, int n_in,
                              void* d_out, int out_size, void* d_ws, size_t ws_size,
                              hipStream_t stream) {
    const float* images = (const float*)d_in[0];
    const float* wih    = (const float*)d_in[1];
    const float* whh    = (const float*)d_in[2];
    const float* bih    = (const float*)d_in[3];
    const float* bhh    = (const float*)d_in[4];
    float* out = (float*)d_out;
    float* ws  = (float*)d_ws;

    float* pose = ws;                       // 107584
    float* hA   = pose + 107584;            // 3442688
    float* hB   = hA + 3442688;             // 3442688
    float* cst  = hB + 3442688;             // 3442688
    float* regb = cst + 3442688;            // 3442688
    // Aliases inside regb (dead between k_lstm of step t and k_register of t+1):
    //   rawp = regb[0 : 186624]          (4 x 16 x 4 x 729)
    //   wT   = regb[262144 : 262144+1843200]  (16 x 4 x 225 x 128)
    // Per-step order: k_register(W regb) -> k_lstm(R regb) -> k_wprep(W wT)
    //                 -> k_localize(R wT, W rawp) -> k_softmax(R rawp). Safe.
    float* rawp = regb;
    float* wT   = regb + 262144;
    float* Wc   = regb + 3442688;           // 131072
    float* bc   = Wc + 131072;              // 512

    hipMemsetAsync(hA, 0, (size_t)3442688 * 4, stream);
    hipMemsetAsync(cst, 0, (size_t)3442688 * 4, stream);
    k_init<<<421, 256, 0, stream>>>(pose);
    k_prep<<<512, 256, 0, stream>>>(wih, whh, bih, bhh, Wc, bc);

    float* hin = hA;
    float* hout = hB;
    for (int t = 0; t < NSTEP; ++t) {
        k_register<<<dim3(7, 4, BB), 256, 0, stream>>>(images, pose, regb, t);
        k_lstm<<<dim3((NROWS + 63) / 64, 8), 256, 0, stream>>>(regb, hin, Wc, bc, hout, cst);
        k_wprep<<<dim3(2, OO, BB), 256, 0, stream>>>(images, wT, t);
        k_maps<<<dim3(53, 4, BB), 256, 0, stream>>>(hout, out, t);
        k_localize<<<dim3(SS, BB, OO), 256, 0, stream>>>(hout, wT, rawp);
        k_softmax<<<BB, 256, 0, stream>>>(rawp, out, pose, t);
        float* tmp = hin; hin = hout; hout = tmp;
    }
}

// Round 9
// 3286.500 us; speedup vs baseline: 2.5460x; 1.4367x over previous
//
#include <hip/hip_runtime.h>
#include <math.h>

#define BB 16
#define TT 16
#define EE 128
#define KS 15
#define MM 41
#define OO 4
#define VR 7
#define SS 27
#define NSTEP 15
#define PP (MM*MM)
#define NROWS (BB*PP)

#define RAWS_OFF 0
#define SPS_OFF  1613760
#define MAPS_OFF 3227520

#define PM 55
#define PMSZ (PM*PM)
#define NPS 4

typedef __attribute__((ext_vector_type(8))) short short8v;
typedef __attribute__((ext_vector_type(4))) float f32x4;
typedef unsigned short ushort;

__device__ __forceinline__ float sigf(float x) { return 1.f / (1.f + expf(-x)); }

__device__ __forceinline__ ushort f2bf(float x) {
    unsigned int u = __float_as_uint(x);
    u += 0x7FFF + ((u >> 16) & 1);
    return (ushort)(u >> 16);
}

__device__ __forceinline__ int rotoff(int o, int r, int c) {
    int ir, ic;
    if (o == 0)      { ir = r;      ic = c;      }
    else if (o == 1) { ir = c;      ic = 14 - r; }
    else if (o == 2) { ir = 14 - r; ic = 14 - c; }
    else             { ir = 14 - c; ic = r;      }
    return ir * 15 + ic;
}

__global__ void k_init(float* __restrict__ pose) {
    int idx = blockIdx.x * 256 + threadIdx.x;
    if (idx < BB * OO * MM * MM) {
        int r = idx % (OO * MM * MM);
        pose[idx] = (r == (20 * MM + 20)) ? 1.f : 0.f;
    }
}

// Wt[jp][k] bf16 (B^T layout for MFMA), jp = jj*4+g; bc[jp] = bih+bhh
__global__ void k_prep(const float* __restrict__ wih, const float* __restrict__ whh,
                       const float* __restrict__ bih, const float* __restrict__ bhh,
                       ushort* __restrict__ Wt, float* __restrict__ bc) {
    int idx = blockIdx.x * 256 + threadIdx.x;   // [0, 512*256)
    int jp = idx >> 8, k = idx & 255;
    int jj = jp >> 2, g = jp & 3, j = g * 128 + jj;
    float v = (k < 128) ? wih[j * 128 + k] : whh[j * 128 + (k - 128)];
    Wt[(size_t)jp * 256 + k] = f2bf(v);
    if (idx < 512) {
        int jj2 = idx >> 2, g2 = idx & 3, j2 = g2 * 128 + jj2;
        bc[idx] = bih[j2] + bhh[j2];
    }
}

// register conv-transpose (R4-verified index math); bf16 output.
// Weight wsm[R*15+C] identical for all 4 o-taps -> factor s = a0+a1+a2+a3.
__global__ __launch_bounds__(256) void k_register(const float* __restrict__ images,
                                                  const float* __restrict__ pose,
                                                  ushort* __restrict__ reg16, int t) {
    __shared__ float ps[OO * PMSZ];
    __shared__ float wsm[225][36];
    const int p0 = blockIdx.x * 256;
    const int eq = blockIdx.y;
    const int b  = blockIdx.z;
    const int tid = threadIdx.x;

    for (int i = tid; i < OO * PMSZ; i += 256) {
        int o = i / PMSZ, rem = i % PMSZ, r = rem / PM, c = rem % PM;
        float v = 0.f;
        if (r >= VR && r < VR + MM && c >= VR && c < VR + MM)
            v = pose[(((size_t)b * OO + o) * MM + (r - VR)) * MM + (c - VR)];
        ps[i] = v;
    }
    const float* img = images + ((size_t)(b * TT + t) * EE + eq * 32) * 225;
    for (int i = tid; i < 32 * 225; i += 256) {
        int e = i / 225, k = i - e * 225;
        wsm[k][e] = img[e * 225 + k];
    }
    __syncthreads();

    const int px = tid & 63;
    const int ec = tid >> 6;
    int pbase[4];
    #pragma unroll
    for (int i = 0; i < 4; ++i) {
        int p = p0 + px + 64 * i;
        int pc = (p < PP) ? p : 0;
        int y = pc / MM, x = pc - y * MM;
        pbase[i] = (y + 2 * VR) * PM + (x + 2 * VR);
    }

    float acc[4][8];
    #pragma unroll
    for (int i = 0; i < 4; ++i)
        #pragma unroll
        for (int j = 0; j < 8; ++j) acc[i][j] = 0.f;

    for (int R = 0; R < 15; ++R) {
        #pragma unroll 5
        for (int C = 0; C < 15; ++C) {
            float4 wv0 = *(const float4*)&wsm[R * 15 + C][ec * 8];
            float4 wv1 = *(const float4*)&wsm[R * 15 + C][ec * 8 + 4];
            #pragma unroll
            for (int i = 0; i < 4; ++i) {
                float a0 = ps[0 * PMSZ + pbase[i] - R * PM - C];
                float a1 = ps[1 * PMSZ + pbase[i] + (C - 14) * PM - R];
                float a2 = ps[2 * PMSZ + pbase[i] + (R - 14) * PM + (C - 14)];
                float a3 = ps[3 * PMSZ + pbase[i] - C * PM + (R - 14)];
                float s = (a0 + a1) + (a2 + a3);
                acc[i][0] += s * wv0.x; acc[i][1] += s * wv0.y;
                acc[i][2] += s * wv0.z; acc[i][3] += s * wv0.w;
                acc[i][4] += s * wv1.x; acc[i][5] += s * wv1.y;
                acc[i][6] += s * wv1.z; acc[i][7] += s * wv1.w;
            }
        }
    }

    #pragma unroll
    for (int i = 0; i < 4; ++i) {
        int p = p0 + px + 64 * i;
        if (p < PP) {
            ushort* dst = reg16 + ((size_t)b * PP + p) * EE + eq * 32 + ec * 8;
            ushort u[8];
            #pragma unroll
            for (int j = 0; j < 8; ++j) u[j] = f2bf(acc[i][j]);
            *(uint4*)dst = *(uint4*)u;
        }
    }
}

// LSTM: bf16 MFMA GEMM (64n x 64jp block, 2x2 waves of 32x32) + fp32 epilogue
// + fused transposed maps write. A = [reg16 | hb16in], B^T = Wt.
__global__ __launch_bounds__(256) void k_lstm(const ushort* __restrict__ reg16,
                                              const ushort* __restrict__ hb16in,
                                              const ushort* __restrict__ Wt,
                                              const float* __restrict__ bc,
                                              float* __restrict__ hout,
                                              ushort* __restrict__ hb16out,
                                              float* __restrict__ cst,
                                              float* __restrict__ out, int t) {
    __shared__ float gsm[64][68];
    __shared__ float h2sm[64][17];
    const int tid = threadIdx.x;
    const int wave = tid >> 6, lane = tid & 63;
    const int wm = wave >> 1, wn = wave & 1;
    const int n0 = blockIdx.x * 64;
    const int jp0 = blockIdx.y * 64;
    const int lr = lane & 15;
    const int lk = (lane >> 4) * 8;

    f32x4 acc[2][2];
    #pragma unroll
    for (int fm = 0; fm < 2; ++fm)
        #pragma unroll
        for (int fn = 0; fn < 2; ++fn) acc[fm][fn] = (f32x4){0.f, 0.f, 0.f, 0.f};

    size_t aoff[2];
    #pragma unroll
    for (int fm = 0; fm < 2; ++fm) {
        int n = n0 + wm * 32 + fm * 16 + lr;
        aoff[fm] = (size_t)((n < NROWS) ? n : (NROWS - 1)) * EE;
    }
    size_t boff[2];
    #pragma unroll
    for (int fn = 0; fn < 2; ++fn)
        boff[fn] = (size_t)(jp0 + wn * 32 + fn * 16 + lr) * 256;

    #pragma unroll
    for (int ks = 0; ks < 8; ++ks) {
        const ushort* src = (ks < 4) ? reg16 : hb16in;
        const int koff = ((ks < 4) ? ks : (ks - 4)) * 32 + lk;
        short8v a0 = *(const short8v*)(src + aoff[0] + koff);
        short8v a1 = *(const short8v*)(src + aoff[1] + koff);
        short8v b0 = *(const short8v*)(Wt + boff[0] + ks * 32 + lk);
        short8v b1 = *(const short8v*)(Wt + boff[1] + ks * 32 + lk);
        acc[0][0] = __builtin_amdgcn_mfma_f32_16x16x32_bf16(a0, b0, acc[0][0], 0, 0, 0);
        acc[0][1] = __builtin_amdgcn_mfma_f32_16x16x32_bf16(a0, b1, acc[0][1], 0, 0, 0);
        acc[1][0] = __builtin_amdgcn_mfma_f32_16x16x32_bf16(a1, b0, acc[1][0], 0, 0, 0);
        acc[1][1] = __builtin_amdgcn_mfma_f32_16x16x32_bf16(a1, b1, acc[1][1], 0, 0, 0);
    }

    #pragma unroll
    for (int fm = 0; fm < 2; ++fm)
        #pragma unroll
        for (int fn = 0; fn < 2; ++fn)
            #pragma unroll
            for (int r = 0; r < 4; ++r)
                gsm[wm * 32 + fm * 16 + (lane >> 4) * 4 + r]
                   [wn * 32 + fn * 16 + (lane & 15)] = acc[fm][fn][r];
    __syncthreads();

    const int jjl = tid & 15;
    const int jj = (jp0 >> 2) + jjl;
    const float4 bv = *(const float4*)(bc + jp0 + jjl * 4);
    #pragma unroll
    for (int i = 0; i < 4; ++i) {
        int nrel = (tid >> 4) * 4 + i;
        int n = n0 + nrel;
        float4 g = *(const float4*)&gsm[nrel][jjl * 4];
        float h2 = 0.f;
        if (n < NROWS) {
            float gi = g.x + bv.x, gf = g.y + bv.y, gg = g.z + bv.z, go = g.w + bv.w;
            size_t off = (size_t)n * EE + jj;
            float cv = cst[off];
            float c2 = sigf(gf) * cv + sigf(gi) * tanhf(gg);
            h2 = sigf(go) * tanhf(c2);
            cst[off] = c2;
            hout[off] = h2;
            hb16out[off] = f2bf(h2);
        }
        h2sm[nrel][jjl] = h2;
    }
    __syncthreads();

    const int nrel2 = tid & 63;
    const int n2 = n0 + nrel2;
    if (n2 < NROWS) {
        const int b2 = n2 / PP, p2 = n2 - b2 * PP;
        const size_t base = MAPS_OFF + ((size_t)(b2 * NSTEP + t) * EE) * PP + p2;
        #pragma unroll
        for (int pass = 0; pass < 4; ++pass) {
            int jl = pass * 4 + (tid >> 6);
            out[base + (size_t)((jp0 >> 2) + jl) * PP] = h2sm[nrel2][jl];
        }
    }
}

__global__ __launch_bounds__(256) void k_wprep(const float* __restrict__ images,
                                               float* __restrict__ wT, int t) {
    __shared__ float img_s[64][225];
    const int eh = blockIdx.x;
    const int o  = blockIdx.y;
    const int b  = blockIdx.z;
    const int tid = threadIdx.x;
    const float* img = images + ((size_t)(b * TT + t + 1) * EE + eh * 64) * 225;
    for (int i = tid; i < 64 * 225; i += 256)
        img_s[i / 225][i % 225] = img[i];
    __syncthreads();
    float* w = wT + ((size_t)(b * OO + o) * 225) * EE + eh * 64;
    for (int j = tid; j < 225 * 64; j += 256) {
        int tap = j >> 6, el = j & 63;
        int r = tap / 15, c = tap - r * 15;
        w[(size_t)tap * EE + el] = img_s[el][rotoff(o, r, c)];
    }
}

__global__ __launch_bounds__(256) void k_localize(const float* __restrict__ h,
                                                  const float* __restrict__ wT,
                                                  float* __restrict__ rawp) {
    const int y  = blockIdx.x;
    const int b  = blockIdx.y;
    const int o  = blockIdx.z;
    const int ps = threadIdx.x >> 6;
    const int lane = threadIdx.x & 63;
    const int eh  = ps & 1;
    const int dyh = ps >> 1;
    const int e   = eh * 64 + lane;
    const int dy0 = dyh ? 8 : 0;
    const int dy1 = dyh ? 15 : 8;

    float acc[SS];
    #pragma unroll
    for (int x = 0; x < SS; ++x) acc[x] = 0.f;

    const float* hb = h + (size_t)b * PP * EE + e;
    const float* wo = wT + (((size_t)b * OO + o) * 225) * EE + e;

    for (int dy = dy0; dy < dy1; ++dy) {
        float hrow[MM];
        const float* hr = hb + (size_t)((y + dy) * MM) * EE;
        #pragma unroll
        for (int c = 0; c < MM; ++c) hrow[c] = hr[(size_t)c * EE];
        const float* wd = wo + (size_t)(dy * 15) * EE;
        #pragma unroll
        for (int dx = 0; dx < 15; ++dx) {
            float wv = wd[(size_t)dx * EE];
            #pragma unroll
            for (int x = 0; x < SS; ++x)
                acc[x] += hrow[x + dx] * wv;
        }
    }

    #pragma unroll
    for (int x = 0; x < SS; ++x) {
        float v = acc[x];
        v += __shfl_xor(v, 1);  v += __shfl_xor(v, 2);  v += __shfl_xor(v, 4);
        v += __shfl_xor(v, 8);  v += __shfl_xor(v, 16); v += __shfl_xor(v, 32);
        if (lane == 0)
            rawp[(((size_t)ps * BB + b) * OO + o) * (SS * SS) + y * SS + x] = v;
    }
}

__global__ __launch_bounds__(256) void k_softmax(const float* __restrict__ rawp,
                                                 float* __restrict__ out,
                                                 float* __restrict__ pose, int t) {
    const int b = blockIdx.x, tid = threadIdx.x;
    const int NTOT = OO * SS * SS;
    __shared__ float sv[OO * SS * SS];
    __shared__ float red[256];

    const float* p0 = rawp + (size_t)b * NTOT;
    for (int i = tid; i < NTOT; i += 256) {
        float s = 0.f;
        #pragma unroll
        for (int q = 0; q < NPS; ++q) s += p0[(size_t)q * BB * NTOT + i];
        sv[i] = s;
    }
    __syncthreads();

    float mx = -3.4e38f;
    for (int i = tid; i < NTOT; i += 256) mx = fmaxf(mx, sv[i]);
    red[tid] = mx; __syncthreads();
    for (int s = 128; s > 0; s >>= 1) {
        if (tid < s) red[tid] = fmaxf(red[tid], red[tid + s]);
        __syncthreads();
    }
    mx = red[0]; __syncthreads();

    float sm = 0.f;
    for (int i = tid; i < NTOT; i += 256) sm += expf(sv[i] - mx);
    red[tid] = sm; __syncthreads();
    for (int s = 128; s > 0; s >>= 1) {
        if (tid < s) red[tid] += red[tid + s];
        __syncthreads();
    }
    const float inv = 1.f / red[0];

    float* rawOut = out + RAWS_OFF + ((size_t)(b * NSTEP + t) * OO) * PP;
    float* spOut  = out + SPS_OFF  + ((size_t)(b * NSTEP + t) * OO) * PP;
    float* pb = pose + (size_t)b * OO * MM * MM;
    for (int i = tid; i < OO * MM * MM; i += 256) {
        int o = i / (MM * MM), rem = i % (MM * MM), yy = rem / MM - VR, xx = rem % MM - VR;
        float rv = 0.f, sv2 = 0.f;
        if ((unsigned)yy < SS && (unsigned)xx < SS) {
            float r = sv[(o * SS + yy) * SS + xx];
            rv = r;
            sv2 = expf(r - mx) * inv;
        }
        rawOut[i] = rv;
        spOut[i] = sv2;
        pb[i] = sv2;
    }
}

extern "C" void kernel_launch(void* const* d_in, const int* in_sizes, int n_in,
                              void* d_out, int out_size, void* d_ws, size_t ws_size,
                              hipStream_t stream) {
    const float* images = (const float*)d_in[0];
    const float* wih    = (const float*)d_in[1];
    const float* whh    = (const float*)d_in[2];
    const float* bih    = (const float*)d_in[3];
    const float* bhh    = (const float*)d_in[4];
    float* out = (float*)d_out;
    float* ws  = (float*)d_ws;

    // layout (float units), total 13,944,384 floats = 55.8 MB
    float*  pose  = ws;                                   // 107,584
    float*  hout  = pose + 107584;                        // 3,442,688 fp32
    float*  cst   = hout + 3442688;                       // 3,442,688 fp32
    ushort* hbA   = (ushort*)(cst + 3442688);             // 1,721,344 float-slots
    ushort* hbB   = (ushort*)(cst + 3442688 + 1721344);   // 1,721,344 float-slots
    float*  regbF = cst + 3442688 + 2 * 1721344;          // 3,442,688 region
    ushort* reg16 = (ushort*)regbF;                       // bf16 reg
    float*  rawp  = regbF;                                // alias (post-lstm)
    float*  wT    = regbF + 262144;                       // alias (post-lstm)
    ushort* Wt    = (ushort*)(regbF + 3442688);           // 65,536 float-slots
    float*  bc    = regbF + 3442688 + 65536;              // 512

    hipMemsetAsync(hbA, 0, (size_t)1721344 * 4, stream);
    hipMemsetAsync(cst, 0, (size_t)3442688 * 4, stream);
    k_init<<<421, 256, 0, stream>>>(pose);
    k_prep<<<512, 256, 0, stream>>>(wih, whh, bih, bhh, Wt, bc);

    ushort* hbin = hbA;
    ushort* hbout = hbB;
    for (int t = 0; t < NSTEP; ++t) {
        k_register<<<dim3(7, 4, BB), 256, 0, stream>>>(images, pose, reg16, t);
        k_lstm<<<dim3(421, 8), 256, 0, stream>>>(reg16, hbin, Wt, bc, hout, hbout, cst, out, t);
        k_wprep<<<dim3(2, OO, BB), 256, 0, stream>>>(images, wT, t);
        k_localize<<<dim3(SS, BB, OO), 256, 0, stream>>>(hout, wT, rawp);
        k_softmax<<<BB, 256, 0, stream>>>(rawp, out, pose, t);
        ushort* tmp = hbin; hbin = hbout; hbout = tmp;
    }
}

// Round 10
// 3261.066 us; speedup vs baseline: 2.5659x; 1.0078x over previous
//
#include <hip/hip_runtime.h>
#include <math.h>

#define BB 16
#define TT 16
#define EE 128
#define KS 15
#define MM 41
#define OO 4
#define VR 7
#define SS 27
#define NSTEP 15
#define PP (MM*MM)
#define NROWS (BB*PP)

#define RAWS_OFF 0
#define SPS_OFF  1613760
#define MAPS_OFF 3227520

#define PM 55
#define PMSZ (PM*PM)
#define NPS 4

typedef __attribute__((ext_vector_type(8))) short short8v;
typedef __attribute__((ext_vector_type(4))) float f32x4;
typedef unsigned short ushort;

__device__ __forceinline__ float sigf(float x) { return 1.f / (1.f + expf(-x)); }

__device__ __forceinline__ ushort f2bf(float x) {
    unsigned int u = __float_as_uint(x);
    u += 0x7FFF + ((u >> 16) & 1);
    return (ushort)(u >> 16);
}
__device__ __forceinline__ float bf2f(ushort u) {
    return __uint_as_float((unsigned int)u << 16);
}

__device__ __forceinline__ int rotoff(int o, int r, int c) {
    int ir, ic;
    if (o == 0)      { ir = r;      ic = c;      }
    else if (o == 1) { ir = c;      ic = 14 - r; }
    else if (o == 2) { ir = 14 - r; ic = 14 - c; }
    else             { ir = 14 - c; ic = r;      }
    return ir * 15 + ic;
}

__global__ void k_init(float* __restrict__ pose) {
    int idx = blockIdx.x * 256 + threadIdx.x;
    if (idx < BB * OO * MM * MM) {
        int r = idx % (OO * MM * MM);
        pose[idx] = (r == (20 * MM + 20)) ? 1.f : 0.f;
    }
}

// Wt[jp][k] bf16 (B^T layout for MFMA), jp = jj*4+g; bc[jp] = bih+bhh
__global__ void k_prep(const float* __restrict__ wih, const float* __restrict__ whh,
                       const float* __restrict__ bih, const float* __restrict__ bhh,
                       ushort* __restrict__ Wt, float* __restrict__ bc) {
    int idx = blockIdx.x * 256 + threadIdx.x;   // [0, 512*256)
    int jp = idx >> 8, k = idx & 255;
    int jj = jp >> 2, g = jp & 3, j = g * 128 + jj;
    float v = (k < 128) ? wih[j * 128 + k] : whh[j * 128 + (k - 128)];
    Wt[(size_t)jp * 256 + k] = f2bf(v);
    if (idx < 512) {
        int jj2 = idx >> 2, g2 = idx & 3, j2 = g2 * 128 + jj2;
        bc[idx] = bih[j2] + bhh[j2];
    }
}

// register conv-transpose (R4-verified index math); bf16 output.
// Weight wsm[R*15+C] identical for all 4 o-taps -> factor s = a0+a1+a2+a3.
__global__ __launch_bounds__(256) void k_register(const float* __restrict__ images,
                                                  const float* __restrict__ pose,
                                                  ushort* __restrict__ reg16, int t) {
    __shared__ float ps[OO * PMSZ];
    __shared__ float wsm[225][36];
    const int p0 = blockIdx.x * 256;
    const int eq = blockIdx.y;
    const int b  = blockIdx.z;
    const int tid = threadIdx.x;

    for (int i = tid; i < OO * PMSZ; i += 256) {
        int o = i / PMSZ, rem = i % PMSZ, r = rem / PM, c = rem % PM;
        float v = 0.f;
        if (r >= VR && r < VR + MM && c >= VR && c < VR + MM)
            v = pose[(((size_t)b * OO + o) * MM + (r - VR)) * MM + (c - VR)];
        ps[i] = v;
    }
    const float* img = images + ((size_t)(b * TT + t) * EE + eq * 32) * 225;
    for (int i = tid; i < 32 * 225; i += 256) {
        int e = i / 225, k = i - e * 225;
        wsm[k][e] = img[e * 225 + k];
    }
    __syncthreads();

    const int px = tid & 63;
    const int ec = tid >> 6;
    int pbase[4];
    #pragma unroll
    for (int i = 0; i < 4; ++i) {
        int p = p0 + px + 64 * i;
        int pc = (p < PP) ? p : 0;
        int y = pc / MM, x = pc - y * MM;
        pbase[i] = (y + 2 * VR) * PM + (x + 2 * VR);
    }

    float acc[4][8];
    #pragma unroll
    for (int i = 0; i < 4; ++i)
        #pragma unroll
        for (int j = 0; j < 8; ++j) acc[i][j] = 0.f;

    for (int R = 0; R < 15; ++R) {
        #pragma unroll 5
        for (int C = 0; C < 15; ++C) {
            float4 wv0 = *(const float4*)&wsm[R * 15 + C][ec * 8];
            float4 wv1 = *(const float4*)&wsm[R * 15 + C][ec * 8 + 4];
            #pragma unroll
            for (int i = 0; i < 4; ++i) {
                float a0 = ps[0 * PMSZ + pbase[i] - R * PM - C];
                float a1 = ps[1 * PMSZ + pbase[i] + (C - 14) * PM - R];
                float a2 = ps[2 * PMSZ + pbase[i] + (R - 14) * PM + (C - 14)];
                float a3 = ps[3 * PMSZ + pbase[i] - C * PM + (R - 14)];
                float s = (a0 + a1) + (a2 + a3);
                acc[i][0] += s * wv0.x; acc[i][1] += s * wv0.y;
                acc[i][2] += s * wv0.z; acc[i][3] += s * wv0.w;
                acc[i][4] += s * wv1.x; acc[i][5] += s * wv1.y;
                acc[i][6] += s * wv1.z; acc[i][7] += s * wv1.w;
            }
        }
    }

    #pragma unroll
    for (int i = 0; i < 4; ++i) {
        int p = p0 + px + 64 * i;
        if (p < PP) {
            ushort* dst = reg16 + ((size_t)b * PP + p) * EE + eq * 32 + ec * 8;
            ushort u[8];
            #pragma unroll
            for (int j = 0; j < 8; ++j) u[j] = f2bf(acc[i][j]);
            *(uint4*)dst = *(uint4*)u;
        }
    }
}

// LSTM: bf16 MFMA GEMM (64n x 64jp block, 2x2 waves of 32x32) + fp32 epilogue
// + fused transposed maps write. A = [reg16 | hb16in], B^T = Wt.
// h is emitted ONLY as bf16 (hb16out) — fp32 hout buffer deleted (localize
// consumes bf16 now); maps output written fp32 from the LDS tile.
__global__ __launch_bounds__(256) void k_lstm(const ushort* __restrict__ reg16,
                                              const ushort* __restrict__ hb16in,
                                              const ushort* __restrict__ Wt,
                                              const float* __restrict__ bc,
                                              ushort* __restrict__ hb16out,
                                              float* __restrict__ cst,
                                              float* __restrict__ out, int t) {
    __shared__ float gsm[64][68];
    __shared__ float h2sm[64][17];
    const int tid = threadIdx.x;
    const int wave = tid >> 6, lane = tid & 63;
    const int wm = wave >> 1, wn = wave & 1;
    const int n0 = blockIdx.x * 64;
    const int jp0 = blockIdx.y * 64;
    const int lr = lane & 15;
    const int lk = (lane >> 4) * 8;

    f32x4 acc[2][2];
    #pragma unroll
    for (int fm = 0; fm < 2; ++fm)
        #pragma unroll
        for (int fn = 0; fn < 2; ++fn) acc[fm][fn] = (f32x4){0.f, 0.f, 0.f, 0.f};

    size_t aoff[2];
    #pragma unroll
    for (int fm = 0; fm < 2; ++fm) {
        int n = n0 + wm * 32 + fm * 16 + lr;
        aoff[fm] = (size_t)((n < NROWS) ? n : (NROWS - 1)) * EE;
    }
    size_t boff[2];
    #pragma unroll
    for (int fn = 0; fn < 2; ++fn)
        boff[fn] = (size_t)(jp0 + wn * 32 + fn * 16 + lr) * 256;

    #pragma unroll
    for (int ks = 0; ks < 8; ++ks) {
        const ushort* src = (ks < 4) ? reg16 : hb16in;
        const int koff = ((ks < 4) ? ks : (ks - 4)) * 32 + lk;
        short8v a0 = *(const short8v*)(src + aoff[0] + koff);
        short8v a1 = *(const short8v*)(src + aoff[1] + koff);
        short8v b0 = *(const short8v*)(Wt + boff[0] + ks * 32 + lk);
        short8v b1 = *(const short8v*)(Wt + boff[1] + ks * 32 + lk);
        acc[0][0] = __builtin_amdgcn_mfma_f32_16x16x32_bf16(a0, b0, acc[0][0], 0, 0, 0);
        acc[0][1] = __builtin_amdgcn_mfma_f32_16x16x32_bf16(a0, b1, acc[0][1], 0, 0, 0);
        acc[1][0] = __builtin_amdgcn_mfma_f32_16x16x32_bf16(a1, b0, acc[1][0], 0, 0, 0);
        acc[1][1] = __builtin_amdgcn_mfma_f32_16x16x32_bf16(a1, b1, acc[1][1], 0, 0, 0);
    }

    #pragma unroll
    for (int fm = 0; fm < 2; ++fm)
        #pragma unroll
        for (int fn = 0; fn < 2; ++fn)
            #pragma unroll
            for (int r = 0; r < 4; ++r)
                gsm[wm * 32 + fm * 16 + (lane >> 4) * 4 + r]
                   [wn * 32 + fn * 16 + (lane & 15)] = acc[fm][fn][r];
    __syncthreads();

    const int jjl = tid & 15;
    const int jj = (jp0 >> 2) + jjl;
    const float4 bv = *(const float4*)(bc + jp0 + jjl * 4);
    #pragma unroll
    for (int i = 0; i < 4; ++i) {
        int nrel = (tid >> 4) * 4 + i;
        int n = n0 + nrel;
        float4 g = *(const float4*)&gsm[nrel][jjl * 4];
        float h2 = 0.f;
        if (n < NROWS) {
            float gi = g.x + bv.x, gf = g.y + bv.y, gg = g.z + bv.z, go = g.w + bv.w;
            size_t off = (size_t)n * EE + jj;
            float cv = cst[off];
            float c2 = sigf(gf) * cv + sigf(gi) * tanhf(gg);
            h2 = sigf(go) * tanhf(c2);
            cst[off] = c2;
            hb16out[off] = f2bf(h2);
        }
        h2sm[nrel][jjl] = h2;
    }
    __syncthreads();

    const int nrel2 = tid & 63;
    const int n2 = n0 + nrel2;
    if (n2 < NROWS) {
        const int b2 = n2 / PP, p2 = n2 - b2 * PP;
        const size_t base = MAPS_OFF + ((size_t)(b2 * NSTEP + t) * EE) * PP + p2;
        #pragma unroll
        for (int pass = 0; pass < 4; ++pass) {
            int jl = pass * 4 + (tid >> 6);
            out[base + (size_t)((jp0 >> 2) + jl) * PP] = h2sm[nrel2][jl];
        }
    }
}

// wprep: wT16[b][o][tap][e] = bf16( rot_o(img[b,t+1])[e][tap] )
__global__ __launch_bounds__(256) void k_wprep(const float* __restrict__ images,
                                               ushort* __restrict__ wT16, int t) {
    __shared__ float img_s[64][225];
    const int eh = blockIdx.x;
    const int o  = blockIdx.y;
    const int b  = blockIdx.z;
    const int tid = threadIdx.x;
    const float* img = images + ((size_t)(b * TT + t + 1) * EE + eh * 64) * 225;
    for (int i = tid; i < 64 * 225; i += 256)
        img_s[i / 225][i % 225] = img[i];
    __syncthreads();
    ushort* w = wT16 + ((size_t)(b * OO + o) * 225) * EE + eh * 64;
    for (int j = tid; j < 225 * 64; j += 256) {
        int tap = j >> 6, el = j & 63;
        int r = tap / 15, c = tap - r * 15;
        w[(size_t)tap * EE + el] = f2bf(img_s[el][rotoff(o, r, c)]);
    }
}

// localize: bf16 h + bf16 weights, fp32 accumulate. Same lane=e structure
// as the R8-verified version; traffic halved vs fp32.
__global__ __launch_bounds__(256) void k_localize(const ushort* __restrict__ h16,
                                                  const ushort* __restrict__ wT16,
                                                  float* __restrict__ rawp) {
    const int y  = blockIdx.x;
    const int b  = blockIdx.y;
    const int o  = blockIdx.z;
    const int ps = threadIdx.x >> 6;
    const int lane = threadIdx.x & 63;
    const int eh  = ps & 1;
    const int dyh = ps >> 1;
    const int e   = eh * 64 + lane;
    const int dy0 = dyh ? 8 : 0;
    const int dy1 = dyh ? 15 : 8;

    float acc[SS];
    #pragma unroll
    for (int x = 0; x < SS; ++x) acc[x] = 0.f;

    const ushort* hb = h16 + (size_t)b * PP * EE + e;
    const ushort* wo = wT16 + (((size_t)b * OO + o) * 225) * EE + e;

    for (int dy = dy0; dy < dy1; ++dy) {
        float hrow[MM];
        const ushort* hr = hb + (size_t)((y + dy) * MM) * EE;
        #pragma unroll
        for (int c = 0; c < MM; ++c) hrow[c] = bf2f(hr[(size_t)c * EE]);
        const ushort* wd = wo + (size_t)(dy * 15) * EE;
        #pragma unroll
        for (int dx = 0; dx < 15; ++dx) {
            float wv = bf2f(wd[(size_t)dx * EE]);
            #pragma unroll
            for (int x = 0; x < SS; ++x)
                acc[x] += hrow[x + dx] * wv;
        }
    }

    #pragma unroll
    for (int x = 0; x < SS; ++x) {
        float v = acc[x];
        v += __shfl_xor(v, 1);  v += __shfl_xor(v, 2);  v += __shfl_xor(v, 4);
        v += __shfl_xor(v, 8);  v += __shfl_xor(v, 16); v += __shfl_xor(v, 32);
        if (lane == 0)
            rawp[(((size_t)ps * BB + b) * OO + o) * (SS * SS) + y * SS + x] = v;
    }
}

__global__ __launch_bounds__(256) void k_softmax(const float* __restrict__ rawp,
                                                 float* __restrict__ out,
                                                 float* __restrict__ pose, int t) {
    const int b = blockIdx.x, tid = threadIdx.x;
    const int NTOT = OO * SS * SS;
    __shared__ float sv[OO * SS * SS];
    __shared__ float red[256];

    const float* p0 = rawp + (size_t)b * NTOT;
    for (int i = tid; i < NTOT; i += 256) {
        float s = 0.f;
        #pragma unroll
        for (int q = 0; q < NPS; ++q) s += p0[(size_t)q * BB * NTOT + i];
        sv[i] = s;
    }
    __syncthreads();

    float mx = -3.4e38f;
    for (int i = tid; i < NTOT; i += 256) mx = fmaxf(mx, sv[i]);
    red[tid] = mx; __syncthreads();
    for (int s = 128; s > 0; s >>= 1) {
        if (tid < s) red[tid] = fmaxf(red[tid], red[tid + s]);
        __syncthreads();
    }
    mx = red[0]; __syncthreads();

    float sm = 0.f;
    for (int i = tid; i < NTOT; i += 256) sm += expf(sv[i] - mx);
    red[tid] = sm; __syncthreads();
    for (int s = 128; s > 0; s >>= 1) {
        if (tid < s) red[tid] += red[tid + s];
        __syncthreads();
    }
    const float inv = 1.f / red[0];

    float* rawOut = out + RAWS_OFF + ((size_t)(b * NSTEP + t) * OO) * PP;
    float* spOut  = out + SPS_OFF  + ((size_t)(b * NSTEP + t) * OO) * PP;
    float* pb = pose + (size_t)b * OO * MM * MM;
    for (int i = tid; i < OO * MM * MM; i += 256) {
        int o = i / (MM * MM), rem = i % (MM * MM), yy = rem / MM - VR, xx = rem % MM - VR;
        float rv = 0.f, sv2 = 0.f;
        if ((unsigned)yy < SS && (unsigned)xx < SS) {
            float r = sv[(o * SS + yy) * SS + xx];
            rv = r;
            sv2 = expf(r - mx) * inv;
        }
        rawOut[i] = rv;
        spOut[i] = sv2;
        pb[i] = sv2;
    }
}

extern "C" void kernel_launch(void* const* d_in, const int* in_sizes, int n_in,
                              void* d_out, int out_size, void* d_ws, size_t ws_size,
                              hipStream_t stream) {
    const float* images = (const float*)d_in[0];
    const float* wih    = (const float*)d_in[1];
    const float* whh    = (const float*)d_in[2];
    const float* bih    = (const float*)d_in[3];
    const float* bhh    = (const float*)d_in[4];
    float* out = (float*)d_out;
    float* ws  = (float*)d_ws;

    // layout (float units), total ~10.5M floats = 42 MB
    float*  pose  = ws;                                   // 107,584
    float*  cst   = pose + 107584;                        // 3,442,688 fp32
    ushort* hbA   = (ushort*)(cst + 3442688);             // 1,721,344 float-slots
    ushort* hbB   = (ushort*)(cst + 3442688 + 1721344);   // 1,721,344 float-slots
    float*  regbF = cst + 3442688 + 2 * 1721344;          // 3,442,688 region
    ushort* reg16 = (ushort*)regbF;                       // bf16 reg (1.72M slots)
    // aliases inside regb region (dead between k_lstm(t) and k_register(t+1)):
    float*  rawp  = regbF;                                // 186,624 floats
    ushort* wT16  = (ushort*)(regbF + 262144);            // 921,600 float-slots
    ushort* Wt    = (ushort*)(regbF + 3442688);           // 65,536 float-slots
    float*  bc    = regbF + 3442688 + 65536;              // 512

    hipMemsetAsync(hbA, 0, (size_t)1721344 * 4, stream);
    hipMemsetAsync(cst, 0, (size_t)3442688 * 4, stream);
    k_init<<<421, 256, 0, stream>>>(pose);
    k_prep<<<512, 256, 0, stream>>>(wih, whh, bih, bhh, Wt, bc);

    ushort* hbin = hbA;
    ushort* hbout = hbB;
    for (int t = 0; t < NSTEP; ++t) {
        k_register<<<dim3(7, 4, BB), 256, 0, stream>>>(images, pose, reg16, t);
        k_lstm<<<dim3(421, 8), 256, 0, stream>>>(reg16, hbin, Wt, bc, hbout, cst, out, t);
        k_wprep<<<dim3(2, OO, BB), 256, 0, stream>>>(images, wT16, t);
        k_localize<<<dim3(SS, BB, OO), 256, 0, stream>>>(hbout, wT16, rawp);
        k_softmax<<<BB, 256, 0, stream>>>(rawp, out, pose, t);
        ushort* tmp = hbin; hbin = hbout; hbout = tmp;
    }
}